// Round 2
// baseline (1807.437 us; speedup 1.0000x reference)
//
#include <hip/hip_runtime.h>
#include <hip/hip_bf16.h>

#define D 128
#define KTOP 3
#define NCLS 10
#define EPS 1e-5f
#define BM 64

// ---------------- degree / CSR build ----------------

__global__ void deg_kernel(const int* __restrict__ src, const int* __restrict__ dst,
                           int* __restrict__ deg_out, int* __restrict__ deg_in, int E) {
    int e = blockIdx.x * blockDim.x + threadIdx.x;
    if (e >= E) return;
    atomicAdd(&deg_out[src[e]], 1);
    atomicAdd(&deg_in[dst[e]], 1);
}

__global__ void rs_kernel(const int* __restrict__ deg_out, const int* __restrict__ deg_in,
                          float* __restrict__ rs_out, float* __restrict__ rs_in, int N) {
    int i = blockIdx.x * blockDim.x + threadIdx.x;
    if (i >= N) return;
    int a = deg_out[i]; if (a < 1) a = 1;
    int b = deg_in[i];  if (b < 1) b = 1;
    rs_out[i] = rsqrtf((float)a);
    rs_in[i]  = rsqrtf((float)b);
}

// single-block exclusive scan of deg_in -> offs[0..N], offs[N]=E
__global__ __launch_bounds__(1024) void scan_kernel(const int* __restrict__ deg,
                                                    int* __restrict__ offs, int N) {
    __shared__ int part[1024];
    int t = threadIdx.x;
    int per = (N + 1023) >> 10;
    int beg = t * per;
    int end = beg + per; if (end > N) end = N;
    int s = 0;
    for (int i = beg; i < end; ++i) s += deg[i];
    part[t] = s;
    __syncthreads();
    for (int off = 1; off < 1024; off <<= 1) {
        int v = (t >= off) ? part[t - off] : 0;
        __syncthreads();
        part[t] += v;
        __syncthreads();
    }
    int run = (t == 0) ? 0 : part[t - 1];
    for (int i = beg; i < end; ++i) { offs[i] = run; run += deg[i]; }
    if (t == 1023) offs[N] = run;
}

__global__ void csr_scatter(const int* __restrict__ src, const int* __restrict__ dst,
                            const int* __restrict__ offs, int* __restrict__ cursor,
                            int* __restrict__ csr, int E) {
    int e = blockIdx.x * blockDim.x + threadIdx.x;
    if (e >= E) return;
    int d = dst[e];
    int pos = offs[d] + atomicAdd(&cursor[d], 1);
    csr[pos] = src[e];
}

// ---------------- fused aggregate + GEMM + bias + BN-stats ----------------
// Block owns BM=64 dst rows. Phase 1: gather/accumulate the normalized
// neighbor sum for each row directly into a swizzled, transposed LDS tile
// (half-wave per row, float4 lanes, edge loop unrolled x4 -> 4 row-loads in
// flight). Phase 2: register-tiled GEMM vs W staged in 32-k LDS chunks.
// Epilogue: +bias, store, and per-column sum/sumsq atomics for BatchNorm.

__global__ __launch_bounds__(256) void agg_gemm(const float* __restrict__ hin,
        const int* __restrict__ offs, const int* __restrict__ csr,
        const float* __restrict__ rs_out, const float* __restrict__ rs_in,
        const float* __restrict__ W, const float* __restrict__ bias,
        float* __restrict__ hout, float* __restrict__ bnsums, int N) {
    __shared__ __align__(16) float At[D][BM];   // swizzled transposed A [k][m]
    __shared__ __align__(16) float Wl[32][D];   // W chunk [k][c]
    int t = threadIdx.x;
    size_t rowBase = (size_t)blockIdx.x * BM;
    int hw = t >> 5;        // half-wave id 0..7
    int l  = t & 31;        // lane in half-wave; covers cols 4l..4l+3

    for (int i = 0; i < BM / 8; ++i) {
        int m = hw + 8 * i;
        int node = (int)rowBase + m;
        int beg = offs[node], end = offs[node + 1];
        float4 a0 = {0.f,0.f,0.f,0.f}, a1 = a0, a2 = a0, a3 = a0;
        int e = beg;
        for (; e + 4 <= end; e += 4) {
            int s0 = csr[e], s1 = csr[e+1], s2 = csr[e+2], s3 = csr[e+3];
            float w0 = rs_out[s0], w1 = rs_out[s1], w2 = rs_out[s2], w3 = rs_out[s3];
            float4 v0 = *reinterpret_cast<const float4*>(hin + (size_t)s0 * D + 4*l);
            float4 v1 = *reinterpret_cast<const float4*>(hin + (size_t)s1 * D + 4*l);
            float4 v2 = *reinterpret_cast<const float4*>(hin + (size_t)s2 * D + 4*l);
            float4 v3 = *reinterpret_cast<const float4*>(hin + (size_t)s3 * D + 4*l);
            a0.x += w0*v0.x; a0.y += w0*v0.y; a0.z += w0*v0.z; a0.w += w0*v0.w;
            a1.x += w1*v1.x; a1.y += w1*v1.y; a1.z += w1*v1.z; a1.w += w1*v1.w;
            a2.x += w2*v2.x; a2.y += w2*v2.y; a2.z += w2*v2.z; a2.w += w2*v2.w;
            a3.x += w3*v3.x; a3.y += w3*v3.y; a3.z += w3*v3.z; a3.w += w3*v3.w;
        }
        for (; e < end; ++e) {
            int s0 = csr[e];
            float w0 = rs_out[s0];
            float4 v0 = *reinterpret_cast<const float4*>(hin + (size_t)s0 * D + 4*l);
            a0.x += w0*v0.x; a0.y += w0*v0.y; a0.z += w0*v0.z; a0.w += w0*v0.w;
        }
        float ri = rs_in[node];
        float4 a;
        a.x = ((a0.x + a1.x) + (a2.x + a3.x)) * ri;
        a.y = ((a0.y + a1.y) + (a2.y + a3.y)) * ri;
        a.z = ((a0.z + a1.z) + (a2.z + a3.z)) * ri;
        a.w = ((a0.w + a1.w) + (a2.w + a3.w)) * ri;
        // swizzled transpose store: element (k=4l+j, m) at At[k][cg*4 + (m&3)]
        int cg = ((m >> 2) ^ (l & 15));
        int co = cg * 4 + (m & 3);
        At[4*l + 0][co] = a.x;
        At[4*l + 1][co] = a.y;
        At[4*l + 2][co] = a.z;
        At[4*l + 3][co] = a.w;
    }

    int tx = t & 15, ty = t >> 4;
    int r0 = tx * 4, c0 = ty * 8;
    float acc[4][8];
#pragma unroll
    for (int i = 0; i < 4; ++i)
#pragma unroll
        for (int j = 0; j < 8; ++j) acc[i][j] = 0.f;

    for (int kc = 0; kc < D; kc += 32) {
        __syncthreads();
        const float4* Wv = reinterpret_cast<const float4*>(W + (size_t)kc * D);
        float4* Wd = reinterpret_cast<float4*>(&Wl[0][0]);
        for (int i = t; i < 32 * D / 4; i += 256) Wd[i] = Wv[i];
        __syncthreads();
#pragma unroll 8
        for (int k = 0; k < 32; ++k) {
            int kk = kc + k;
            float4 av4 = *reinterpret_cast<const float4*>(&At[kk][(tx ^ ((kk >> 2) & 15)) << 2]);
            float4 w0 = *reinterpret_cast<const float4*>(&Wl[k][c0]);
            float4 w1 = *reinterpret_cast<const float4*>(&Wl[k][c0 + 4]);
            float av[4] = {av4.x, av4.y, av4.z, av4.w};
            float wv[8] = {w0.x, w0.y, w0.z, w0.w, w1.x, w1.y, w1.z, w1.w};
#pragma unroll
            for (int i = 0; i < 4; ++i)
#pragma unroll
                for (int j = 0; j < 8; ++j) acc[i][j] += av[i] * wv[j];
        }
    }

    float4 b0 = *reinterpret_cast<const float4*>(&bias[c0]);
    float4 b1 = *reinterpret_cast<const float4*>(&bias[c0 + 4]);
    float bv[8] = {b0.x, b0.y, b0.z, b0.w, b1.x, b1.y, b1.z, b1.w};
    float cs[8], cq[8];
#pragma unroll
    for (int j = 0; j < 8; ++j) { cs[j] = 0.f; cq[j] = 0.f; }
#pragma unroll
    for (int i = 0; i < 4; ++i) {
#pragma unroll
        for (int j = 0; j < 8; ++j) {
            float v = acc[i][j] + bv[j];
            acc[i][j] = v;
            cs[j] += v;
            cq[j] += v * v;
        }
    }
#pragma unroll
    for (int i = 0; i < 4; ++i) {
        size_t row = rowBase + r0 + i;
        float4 o0, o1;
        o0.x = acc[i][0]; o0.y = acc[i][1]; o0.z = acc[i][2]; o0.w = acc[i][3];
        o1.x = acc[i][4]; o1.y = acc[i][5]; o1.z = acc[i][6]; o1.w = acc[i][7];
        *reinterpret_cast<float4*>(&hout[row * D + c0])     = o0;
        *reinterpret_cast<float4*>(&hout[row * D + c0 + 4]) = o1;
    }
    // reduce sums over the 16 tx lanes of this ty-group (contiguous in wave)
#pragma unroll
    for (int o = 1; o < 16; o <<= 1) {
#pragma unroll
        for (int j = 0; j < 8; ++j) {
            cs[j] += __shfl_xor(cs[j], o, 64);
            cq[j] += __shfl_xor(cq[j], o, 64);
        }
    }
    if (tx == 0) {
#pragma unroll
        for (int j = 0; j < 8; ++j) {
            atomicAdd(&bnsums[c0 + j], cs[j]);
            atomicAdd(&bnsums[D + c0 + j], cq[j]);
        }
    }
}

// ---------------- BatchNorm finalize + apply ----------------

__global__ void bn_final(const float* __restrict__ sums, const float* __restrict__ g,
                         const float* __restrict__ bt, float* __restrict__ sc,
                         float* __restrict__ sh, int N) {
    int c = threadIdx.x;
    if (c >= D) return;
    float mu  = sums[c] / (float)N;
    float var = sums[D + c] / (float)N - mu * mu;
    float inv = rsqrtf(var + EPS);
    float scale = g[c] * inv;
    sc[c] = scale;
    sh[c] = bt[c] - mu * scale;
}

__global__ __launch_bounds__(256) void bn_apply_relu_max(float* __restrict__ h,
        const float* __restrict__ sc, const float* __restrict__ sh,
        float* __restrict__ nodemax, int N) {
    int wv   = (blockIdx.x * 256 + threadIdx.x) >> 6;
    int lane = threadIdx.x & 63;
    if (wv >= N) return;
    float2 v = *reinterpret_cast<const float2*>(h + (size_t)wv * D + lane * 2);
    float2 a = *reinterpret_cast<const float2*>(sc + lane * 2);
    float2 b = *reinterpret_cast<const float2*>(sh + lane * 2);
    float x = fmaxf(v.x * a.x + b.x, 0.f);
    float y = fmaxf(v.y * a.y + b.y, 0.f);
    float2 o; o.x = x; o.y = y;
    *reinterpret_cast<float2*>(h + (size_t)wv * D + lane * 2) = o;
    float m = fmaxf(x, y);
#pragma unroll
    for (int d = 32; d > 0; d >>= 1) m = fmaxf(m, __shfl_down(m, d, 64));
    if (lane == 0) nodemax[wv] = m;
}

__global__ __launch_bounds__(256) void rowmax_kernel(const float* __restrict__ h,
                                                     float* __restrict__ nodemax, int N) {
    int wv   = (blockIdx.x * 256 + threadIdx.x) >> 6;
    int lane = threadIdx.x & 63;
    if (wv >= N) return;
    float2 v = *reinterpret_cast<const float2*>(h + (size_t)wv * D + lane * 2);
    float m = fmaxf(v.x, v.y);
#pragma unroll
    for (int d = 32; d > 0; d >>= 1) m = fmaxf(m, __shfl_down(m, d, 64));
    if (lane == 0) nodemax[wv] = m;
}

// ---------------- SortPool top-k + head ----------------
// one block per graph; LDS tree argmax x3 with (value desc, index asc) order
__global__ __launch_bounds__(256) void topk_kernel(const float* __restrict__ nodemax,
                                                   int* __restrict__ tk, int NPG) {
    int g = blockIdx.x;
    int t = threadIdx.x;
    __shared__ float ov[256];
    __shared__ float sv[256];
    __shared__ int   si[256];
    ov[t] = (t < NPG) ? nodemax[(size_t)g * NPG + t] : -3.4e38f;
    __syncthreads();
    for (int sel = 0; sel < 3; ++sel) {
        sv[t] = ov[t]; si[t] = t;
        __syncthreads();
        for (int s = 128; s > 0; s >>= 1) {
            if (t < s) {
                float a = sv[t], b = sv[t + s];
                int ia = si[t], ib = si[t + s];
                if (b > a || (b == a && ib < ia)) { sv[t] = b; si[t] = ib; }
            }
            __syncthreads();
        }
        if (t == 0) {
            tk[g * 3 + sel] = g * NPG + si[0];
            ov[si[0]] = -3.4e38f;
        }
        __syncthreads();
    }
}

__global__ void score_init(float* __restrict__ score, const float* __restrict__ b0,
                           const float* __restrict__ b1, const float* __restrict__ b2,
                           const float* __restrict__ b3, int G) {
    int i = blockIdx.x * blockDim.x + threadIdx.x;
    if (i >= G * NCLS) return;
    int c = i % NCLS;
    score[i] = b0[c] + b1[c] + b2[c] + b3[c];
}

// one block (128 thr) per (graph, k): sort node features asc, dot with Pw rows
__global__ __launch_bounds__(128) void sort_head(const float* __restrict__ h,
        const int* __restrict__ tk, const float* __restrict__ Pw,
        float* __restrict__ score, int G) {
    int b = blockIdx.x;
    int g = b / KTOP, k = b - g * KTOP;
    int node = tk[b];
    int t = threadIdx.x;
    __shared__ float s[D];
    __shared__ float red[2][NCLS];
    s[t] = h[(size_t)node * D + t];
    __syncthreads();
    for (int size = 2; size <= D; size <<= 1) {
        for (int stride = size >> 1; stride > 0; stride >>= 1) {
            int ixj = t ^ stride;
            if (ixj > t) {
                float a = s[t], c = s[ixj];
                bool up = ((t & size) == 0);
                if ((a > c) == up) { s[t] = c; s[ixj] = a; }
            }
            __syncthreads();
        }
    }
    float v = s[t];
    const float* pw = Pw + (size_t)(k * D + t) * NCLS;
    float part[NCLS];
#pragma unroll
    for (int c = 0; c < NCLS; ++c) part[c] = v * pw[c];
    int lane = t & 63, wid = t >> 6;
#pragma unroll
    for (int c = 0; c < NCLS; ++c) {
        float x = part[c];
#pragma unroll
        for (int o = 32; o > 0; o >>= 1) x += __shfl_down(x, o, 64);
        if (lane == 0) red[wid][c] = x;
    }
    __syncthreads();
    if (t < NCLS) atomicAdd(&score[g * NCLS + t], red[0][t] + red[1][t]);
}

// ---------------- launch ----------------

extern "C" void kernel_launch(void* const* d_in, const int* in_sizes, int n_in,
                              void* d_out, int out_size, void* d_ws, size_t ws_size,
                              hipStream_t stream) {
    const float* x   = (const float*)d_in[0];
    const int*   src = (const int*)d_in[1];
    const int*   dst = (const int*)d_in[2];
    const float* W[3]  = {(const float*)d_in[5],  (const float*)d_in[9],  (const float*)d_in[13]};
    const float* bb[3] = {(const float*)d_in[6],  (const float*)d_in[10], (const float*)d_in[14]};
    const float* gg[3] = {(const float*)d_in[7],  (const float*)d_in[11], (const float*)d_in[15]};
    const float* bt[3] = {(const float*)d_in[8],  (const float*)d_in[12], (const float*)d_in[16]};
    const float* Pw[4] = {(const float*)d_in[17], (const float*)d_in[19], (const float*)d_in[21], (const float*)d_in[23]};
    const float* Pb[4] = {(const float*)d_in[18], (const float*)d_in[20], (const float*)d_in[22], (const float*)d_in[24]};

    int N = in_sizes[0] / D;
    int E = in_sizes[1];
    int G = out_size / NCLS;
    int NPG = N / G;
    float* score = (float*)d_out;

    size_t NF = (size_t)N * D;
    float* fws     = (float*)d_ws;
    float* H       = fws;
    float* T       = H + NF;
    float* rs_out  = T + NF;
    float* rs_in   = rs_out + N;
    float* nodemax = rs_in + N;
    float* bnsums  = nodemax + N;      // 3 layers x 2*D
    float* bscale  = bnsums + 6 * D;   // D
    float* bshift  = bscale + D;       // D
    int* deg_out = (int*)(bshift + D);
    int* deg_in  = deg_out + N;
    int* cursor  = deg_in + N;
    int* offs    = cursor + N;         // N+1
    int* csr     = offs + N + 1;       // E
    int* tk      = csr + E;            // G*3

    // degrees + CSR (rebuilt deterministically per call)
    hipMemsetAsync(deg_out, 0, sizeof(int) * (size_t)3 * N, stream);  // deg_out, deg_in, cursor
    hipMemsetAsync(bnsums, 0, sizeof(float) * 6 * D, stream);
    deg_kernel<<<(E + 255) / 256, 256, 0, stream>>>(src, dst, deg_out, deg_in, E);
    rs_kernel<<<(N + 255) / 256, 256, 0, stream>>>(deg_out, deg_in, rs_out, rs_in, N);
    scan_kernel<<<1, 1024, 0, stream>>>(deg_in, offs, N);
    csr_scatter<<<(E + 255) / 256, 256, 0, stream>>>(src, dst, offs, cursor, csr, E);

    score_init<<<(G * NCLS + 255) / 256, 256, 0, stream>>>(score, Pb[0], Pb[1], Pb[2], Pb[3], G);

    // rep 0 head (raw x)
    rowmax_kernel<<<N / 4, 256, 0, stream>>>(x, nodemax, N);
    topk_kernel<<<G, 256, 0, stream>>>(nodemax, tk, NPG);
    sort_head<<<G * KTOP, D, 0, stream>>>(x, tk, Pw[0], score, G);

    const float* hin = x;
    float* bufs[3] = {H, T, H};
    for (int l = 0; l < 3; ++l) {
        float* hout = bufs[l];
        float* bns  = bnsums + l * 2 * D;
        agg_gemm<<<N / BM, 256, 0, stream>>>(hin, offs, csr, rs_out, rs_in,
                                             W[l], bb[l], hout, bns, N);
        bn_final<<<1, D, 0, stream>>>(bns, gg[l], bt[l], bscale, bshift, N);
        bn_apply_relu_max<<<N / 4, 256, 0, stream>>>(hout, bscale, bshift, nodemax, N);
        topk_kernel<<<G, 256, 0, stream>>>(nodemax, tk, NPG);
        sort_head<<<G * KTOP, D, 0, stream>>>(hout, tk, Pw[l + 1], score, G);
        hin = hout;
    }
}